// Round 3
// baseline (77.493 us; speedup 1.0000x reference)
//
#include <hip/hip_runtime.h>
#include <math.h>

// FGN layer via bf16 MFMA with split-K x4:
//   res = (X @ W^T + bias) * g
//   g   = exp(-(A' @ Gw^T + const_z)),  A' = [X | X^2],  Gw = [-2*c*s^2 | s^2],
//   s = min(ic, 1e8),  const_z = sum_i c^2 s^2.
// Main kernel: 1024 blocks (grid 32x32) x 256 threads. Each block = one 32x32
// output tile; its 4 waves split K=512 into 4x128 chunks (waves 0,1 also do
// the K=256 linear GEMM), partials reduced through LDS (stride-17 pad =
// conflict-free), fused exp/bias epilogue. 4096 waves = 4 waves/SIMD for
// latency hiding; total L2 traffic same as the 1-wave/SIMD version.

typedef __attribute__((ext_vector_type(8))) short short8;
typedef __attribute__((ext_vector_type(4))) float floatx4;

#define BDIM   1024
#define INDIM  256
#define OUTDIM 1024
#define AK     512   // A' row length: [x | x^2]
#define WK     256   // W row length
#define GK     512   // Gw row length: [-2cs^2 | s^2]

__device__ __forceinline__ unsigned short f2bf(float f) {
    union { float f; unsigned u; } v; v.f = f;
    unsigned r = v.u + 0x7FFFu + ((v.u >> 16) & 1u);   // RNE
    return (unsigned short)(r >> 16);
}

// Fused preprocessing.
// Blocks [0,256): convert X -> A' = [bf16(x) | bf16(x^2)]
// Blocks [256,512): per out-row z: Wb=bf16(W), Gw=[-2cs^2 | s^2], const_z
__global__ __launch_bounds__(256)
void fgn_prep(const float* __restrict__ X, const float* __restrict__ W,
              const float* __restrict__ C, const float* __restrict__ IC,
              unsigned short* __restrict__ Ap, unsigned short* __restrict__ Wb,
              unsigned short* __restrict__ Gw, float* __restrict__ Cz)
{
    const int bid = blockIdx.x;
    if (bid < 256) {
        const int f   = bid * 256 + threadIdx.x;
        const int row = f >> 6;
        const int kq  = (f & 63) << 2;
        float4 x = *(const float4*)&X[row * INDIM + kq];
        ushort4 a, b;
        a.x = f2bf(x.x);      a.y = f2bf(x.y);      a.z = f2bf(x.z);      a.w = f2bf(x.w);
        b.x = f2bf(x.x*x.x);  b.y = f2bf(x.y*x.y);  b.z = f2bf(x.z*x.z);  b.w = f2bf(x.w*x.w);
        *(ushort4*)&Ap[row * AK + kq]         = a;
        *(ushort4*)&Ap[row * AK + INDIM + kq] = b;
    } else {
        const int z    = (bid - 256) * 4 + (threadIdx.x >> 6);
        const int lane = threadIdx.x & 63;
        const int k    = lane << 2;
        float4 w  = *(const float4*)&W [z * INDIM + k];
        float4 c  = *(const float4*)&C [z * INDIM + k];
        float4 ic = *(const float4*)&IC[z * INDIM + k];
        float s0 = fminf(ic.x, 1e8f), s1 = fminf(ic.y, 1e8f);
        float s2 = fminf(ic.z, 1e8f), s3 = fminf(ic.w, 1e8f);
        float q0 = s0*s0, q1 = s1*s1, q2 = s2*s2, q3 = s3*s3;
        ushort4 wv, w2v, s2v;
        wv.x  = f2bf(w.x);            wv.y  = f2bf(w.y);
        wv.z  = f2bf(w.z);            wv.w  = f2bf(w.w);
        w2v.x = f2bf(-2.f*c.x*q0);    w2v.y = f2bf(-2.f*c.y*q1);
        w2v.z = f2bf(-2.f*c.z*q2);    w2v.w = f2bf(-2.f*c.w*q3);
        s2v.x = f2bf(q0);             s2v.y = f2bf(q1);
        s2v.z = f2bf(q2);             s2v.w = f2bf(q3);
        *(ushort4*)&Wb[z * WK + k]         = wv;
        *(ushort4*)&Gw[z * GK + k]         = w2v;
        *(ushort4*)&Gw[z * GK + INDIM + k] = s2v;
        float cc = c.x*c.x*q0 + c.y*c.y*q1 + c.z*c.z*q2 + c.w*c.w*q3;
        #pragma unroll
        for (int off = 32; off; off >>= 1) cc += __shfl_xor(cc, off);
        if (lane == 0) Cz[z] = cc;
    }
}

__global__ __launch_bounds__(256)
void fgn_main(const unsigned short* __restrict__ Ap, const unsigned short* __restrict__ Wb,
              const unsigned short* __restrict__ Gw, const float* __restrict__ Bias,
              const float* __restrict__ Cz, float* __restrict__ Out)
{
    const int n0   = blockIdx.x * 32;
    const int m0   = blockIdx.y * 32;
    const int t    = threadIdx.x;
    const int w    = t >> 6;          // wave id 0..3 = K chunk
    const int lane = t & 63;
    const int r    = lane & 15;
    const int q    = lane >> 4;

    __shared__ float sL[2 * 64 * 17];   // waves 0,1 linear partials
    __shared__ float sG[4 * 64 * 17];   // all waves gaussian partials

    // short8 index base for this wave's K chunk (w*128 bf16 = w*16 short8)
    const int kb = w * 16;
    const short8* A0 = (const short8*)(Ap + (size_t)(m0 +      r) * AK) + q + kb;
    const short8* A1 = (const short8*)(Ap + (size_t)(m0 + 16 + r) * AK) + q + kb;
    const short8* G0 = (const short8*)(Gw + (size_t)(n0 +      r) * GK) + q + kb;
    const short8* G1 = (const short8*)(Gw + (size_t)(n0 + 16 + r) * GK) + q + kb;
    const short8* W0 = (const short8*)(Wb + (size_t)(n0 +      r) * WK) + q + kb;
    const short8* W1 = (const short8*)(Wb + (size_t)(n0 + 16 + r) * WK) + q + kb;

    floatx4 zero = {0.f, 0.f, 0.f, 0.f};
    floatx4 accL[2][2] = {{zero, zero}, {zero, zero}};
    floatx4 accG[2][2] = {{zero, zero}, {zero, zero}};

    #pragma unroll
    for (int kk = 0; kk < 4; ++kk) {
        short8 a0 = A0[kk * 4];
        short8 a1 = A1[kk * 4];
        short8 g0 = G0[kk * 4];
        short8 g1 = G1[kk * 4];
        accG[0][0] = __builtin_amdgcn_mfma_f32_16x16x32_bf16(a0, g0, accG[0][0], 0, 0, 0);
        accG[0][1] = __builtin_amdgcn_mfma_f32_16x16x32_bf16(a0, g1, accG[0][1], 0, 0, 0);
        accG[1][0] = __builtin_amdgcn_mfma_f32_16x16x32_bf16(a1, g0, accG[1][0], 0, 0, 0);
        accG[1][1] = __builtin_amdgcn_mfma_f32_16x16x32_bf16(a1, g1, accG[1][1], 0, 0, 0);
        if (w < 2) {   // wave-uniform branch: only K<256 has the linear GEMM
            short8 w0 = W0[kk * 4];
            short8 w1 = W1[kk * 4];
            accL[0][0] = __builtin_amdgcn_mfma_f32_16x16x32_bf16(a0, w0, accL[0][0], 0, 0, 0);
            accL[0][1] = __builtin_amdgcn_mfma_f32_16x16x32_bf16(a0, w1, accL[0][1], 0, 0, 0);
            accL[1][0] = __builtin_amdgcn_mfma_f32_16x16x32_bf16(a1, w0, accL[1][0], 0, 0, 0);
            accL[1][1] = __builtin_amdgcn_mfma_f32_16x16x32_bf16(a1, w1, accL[1][1], 0, 0, 0);
        }
    }

    // ---- write partials to LDS (stride 17: 17*l mod 32 is a bijection -> conflict-free)
    #pragma unroll
    for (int mt = 0; mt < 2; ++mt)
        #pragma unroll
        for (int nt = 0; nt < 2; ++nt)
            #pragma unroll
            for (int reg = 0; reg < 4; ++reg) {
                const int f = mt * 8 + nt * 4 + reg;
                sG[(w * 64 + lane) * 17 + f] = accG[mt][nt][reg];
                if (w < 2) sL[(w * 64 + lane) * 17 + f] = accL[mt][nt][reg];
            }
    __syncthreads();

    // ---- reduce + epilogue: thread t handles frag slots f = (t>>6)*4 .. +4 at lane l
    const int l  = lane;
    const int gr = w;
    const int li = l & 15;
    const float bias0 = Bias[n0 + li],  bias1 = Bias[n0 + 16 + li];
    const float cz0   = Cz[n0 + li],    cz1   = Cz[n0 + 16 + li];
    float* OutR = Out;
    float* OutG = Out + (size_t)BDIM * OUTDIM;
    #pragma unroll
    for (int j = 0; j < 4; ++j) {
        const int f = gr * 4 + j;
        const float Ls = sL[l * 17 + f] + sL[(64 + l) * 17 + f];
        const float Gs = sG[l * 17 + f]         + sG[(64 + l) * 17 + f]
                       + sG[(128 + l) * 17 + f] + sG[(192 + l) * 17 + f];
        const int mt = f >> 3, nt = (f >> 2) & 1, reg = f & 3;
        const int m = m0 + mt * 16 + (l >> 4) * 4 + reg;
        const int n = n0 + nt * 16 + li;
        const float g   = expf(-(Gs + (nt ? cz1 : cz0)));
        const float res = (Ls + (nt ? bias1 : bias0)) * g;
        OutR[(size_t)m * OUTDIM + n] = res;
        OutG[(size_t)m * OUTDIM + n] = g;
    }
}

extern "C" void kernel_launch(void* const* d_in, const int* in_sizes, int n_in,
                              void* d_out, int out_size, void* d_ws, size_t ws_size,
                              hipStream_t stream) {
    const float* X    = (const float*)d_in[0];
    const float* W    = (const float*)d_in[1];
    const float* Bias = (const float*)d_in[2];
    const float* C    = (const float*)d_in[3];
    const float* IC   = (const float*)d_in[4];
    float* Out = (float*)d_out;

    unsigned short* Ap = (unsigned short*)d_ws;                  // 1 MB
    unsigned short* Wb = Ap + (size_t)BDIM * AK;                 // 0.5 MB
    unsigned short* Gw = Wb + (size_t)OUTDIM * WK;               // 1 MB
    float*          Cz = (float*)(Gw + (size_t)OUTDIM * GK);     // 4 KB

    fgn_prep<<<512, 256, 0, stream>>>(X, W, C, IC, Ap, Wb, Gw, Cz);
    dim3 grid(OUTDIM / 32, BDIM / 32);
    fgn_main<<<grid, 256, 0, stream>>>(Ap, Wb, Gw, Bias, Cz, Out);
}